// Round 11
// baseline (493.145 us; speedup 1.0000x reference)
//
#include <hip/hip_runtime.h>
#include <hip/hip_bf16.h>
#include <math.h>

#define HH 96
#define WWID 96
#define HW 9216
#define CC 256
#define BB 2
#define PROW 104
#define PCOL 128
#define PPX (PROW * PCOL)   // 13312

typedef float f32x4 __attribute__((ext_vector_type(4)));
typedef _Float16 f16x8 __attribute__((ext_vector_type(8)));

__device__ inline unsigned int pack2h(float a, float b) {
  unsigned short ua = __builtin_bit_cast(unsigned short, (_Float16)a);
  unsigned short ub = __builtin_bit_cast(unsigned short, (_Float16)b);
  return (unsigned int)ua | ((unsigned int)ub << 16);
}
__device__ inline float h_lo(unsigned int u) {
  return (float)__builtin_bit_cast(_Float16, (unsigned short)(u & 0xffffu));
}
__device__ inline float h_hi(unsigned int u) {
  return (float)__builtin_bit_cast(_Float16, (unsigned short)(u >> 16));
}

// async 16B global->LDS: lds dest = wave-uniform base + lane*16
__device__ inline void gload_lds16(const void* g, void* l) {
  __builtin_amdgcn_global_load_lds(
      (const __attribute__((address_space(1))) void*)g,
      (__attribute__((address_space(3))) void*)l, 16, 0, 0);
}

// in_w [C][C] -> wT [k][c]
__global__ void k_transpose_w(const float* __restrict__ in_w, float* __restrict__ wT) {
  int k = blockIdx.x, c = threadIdx.x;
  wT[k * CC + c] = in_w[c * CC + k];
}

// pack conv3x3 weights -> Whf [3 d][256 co][2304 k], k = j*256+ci, fp16; bias Ball[3*256]
__global__ void k_packw(const float* __restrict__ ow1, const float* __restrict__ ob1,
                        const float* __restrict__ mw1, const float* __restrict__ mb1,
                        const float* __restrict__ ow2, const float* __restrict__ ob2,
                        const float* __restrict__ mw2, const float* __restrict__ mb2,
                        const float* __restrict__ ow4, const float* __restrict__ ob4,
                        const float* __restrict__ mw4, const float* __restrict__ mb4,
                        _Float16* __restrict__ Whf, float* __restrict__ Ball) {
  int idx = blockIdx.x * 256 + threadIdx.x;
  if (idx >= 3 * 256 * 2304) return;
  int d = idx / (256 * 2304);
  int rem = idx - d * 256 * 2304;
  int co = rem / 2304;
  int k = rem - co * 2304;
  int j = k >> 8, ci = k & 255;
  const float* ow = d == 0 ? ow1 : (d == 1 ? ow2 : ow4);
  const float* mw = d == 0 ? mw1 : (d == 1 ? mw2 : mw4);
  float v = 0.f;
  if (co < 144) v = ow[co * 2304 + ci * 9 + j];
  else if (co < 216) v = mw[(co - 144) * 2304 + ci * 9 + j];
  Whf[idx] = (_Float16)v;
  if (idx < 768) {
    int dd = idx >> 8, cc = idx & 255;
    const float* obv = dd == 0 ? ob1 : (dd == 1 ? ob2 : ob4);
    const float* mbv = dd == 0 ? mb1 : (dd == 1 ? mb2 : mb4);
    float bv = 0.f;
    if (cc < 144) bv = obv[cc];
    else if (cc < 216) bv = mbv[cc - 144];
    Ball[idx] = bv;
  }
}

// conv1x1 + LayerNorm for the query. Writes fp32 NHWC q_hwc AND fp16 qpad
// (zero-padded grid; border pre-zeroed by hipMemsetAsync). float4 LDS reads.
__global__ void k_conv1_ln_q(const float* __restrict__ qin, const float* __restrict__ wT,
                             const float* __restrict__ in_b, const float* __restrict__ ln_g,
                             const float* __restrict__ ln_b, float* __restrict__ q_hwc,
                             _Float16* __restrict__ qpad) {
  int bx = blockIdx.x;
  int b = bx / 288;
  int hw0 = (bx % 288) * 32;
  int t = threadIdx.x;
  int lane = t & 63;
  int wv_id = t >> 6;
  __shared__ float xs[32 * 260];
  const float* qb = qin + (size_t)b * CC * HW;
  #pragma unroll
  for (int i = 0; i < 32; ++i) {
    int idx = t + i * 256;
    int p = idx & 31;
    int k = idx >> 5;
    xs[p * 260 + k] = qb[k * HW + hw0 + p];
  }
  __syncthreads();
  float acc[8][4];
  #pragma unroll
  for (int p = 0; p < 8; ++p) { acc[p][0]=0.f; acc[p][1]=0.f; acc[p][2]=0.f; acc[p][3]=0.f; }
  const float4* wT4 = (const float4*)wT;
  int p0 = wv_id * 8;
  for (int k = 0; k < 256; k += 4) {
    float4 w0 = wT4[(k + 0) * 64 + lane];
    float4 w1 = wT4[(k + 1) * 64 + lane];
    float4 w2 = wT4[(k + 2) * 64 + lane];
    float4 w3 = wT4[(k + 3) * 64 + lane];
    #pragma unroll
    for (int p = 0; p < 8; ++p) {
      float4 xv = *(const float4*)&xs[(p0 + p) * 260 + k];
      acc[p][0] += w0.x * xv.x + w1.x * xv.y + w2.x * xv.z + w3.x * xv.w;
      acc[p][1] += w0.y * xv.x + w1.y * xv.y + w2.y * xv.z + w3.y * xv.w;
      acc[p][2] += w0.z * xv.x + w1.z * xv.y + w2.z * xv.z + w3.z * xv.w;
      acc[p][3] += w0.w * xv.x + w1.w * xv.y + w2.w * xv.z + w3.w * xv.w;
    }
  }
  float4 bb = ((const float4*)in_b)[lane];
  float4 g4 = ((const float4*)ln_g)[lane];
  float4 b4 = ((const float4*)ln_b)[lane];
  #pragma unroll
  for (int p = 0; p < 8; ++p) {
    float y0 = acc[p][0] + bb.x, y1 = acc[p][1] + bb.y;
    float y2 = acc[p][2] + bb.z, y3 = acc[p][3] + bb.w;
    float s1 = y0 + y1 + y2 + y3;
    float s2 = y0*y0 + y1*y1 + y2*y2 + y3*y3;
    #pragma unroll
    for (int off = 32; off; off >>= 1) { s1 += __shfl_xor(s1, off); s2 += __shfl_xor(s2, off); }
    float mu = s1 * (1.f / 256.f);
    float rstd = rsqrtf(s2 * (1.f / 256.f) - mu * mu + 1e-5f);
    float4 o;
    o.x = (y0 - mu) * rstd * g4.x + b4.x;
    o.y = (y1 - mu) * rstd * g4.y + b4.y;
    o.z = (y2 - mu) * rstd * g4.z + b4.z;
    o.w = (y3 - mu) * rstd * g4.w + b4.w;
    int hw = hw0 + p0 + p;
    ((float4*)q_hwc)[((size_t)b * HW + hw) * 64 + lane] = o;
    int hh = hw / 96, ww = hw - hh * 96;
    int ppx = (hh + 4) * PCOL + ww + 4;
    struct alignas(8) h4 { _Float16 h[4]; };
    h4 oh;
    oh.h[0] = (_Float16)o.x; oh.h[1] = (_Float16)o.y;
    oh.h[2] = (_Float16)o.z; oh.h[3] = (_Float16)o.w;
    *(h4*)(qpad + ((size_t)b * PPX + ppx) * CC + lane * 4) = oh;
  }
}

// supports: conv1x1 + LN per (b,e) image of 9 positions; also pooled max.
__global__ void k_conv1_ln_s(const float* __restrict__ sup, const float* __restrict__ wT,
                             const float* __restrict__ in_b, const float* __restrict__ ln_g,
                             const float* __restrict__ ln_b, float* __restrict__ s_ln,
                             float* __restrict__ pooled) {
  int img = blockIdx.x;  // b*3+e
  int t = threadIdx.x;
  __shared__ float xs[2304];
  __shared__ float red1[256], red2[256];
  #pragma unroll
  for (int p = 0; p < 9; ++p) xs[t * 9 + p] = sup[(size_t)img * 2304 + t * 9 + p];
  __syncthreads();
  float acc[9];
  #pragma unroll
  for (int p = 0; p < 9; ++p) acc[p] = 0.f;
  for (int k = 0; k < 256; ++k) {
    float wv = wT[k * CC + t];
    #pragma unroll
    for (int p = 0; p < 9; ++p) acc[p] += wv * xs[k * 9 + p];
  }
  float bias = in_b[t];
  #pragma unroll
  for (int p = 0; p < 9; ++p) acc[p] += bias;
  float g = ln_g[t], be = ln_b[t];
  float vals[9];
  #pragma unroll
  for (int p = 0; p < 9; ++p) {
    red1[t] = acc[p]; red2[t] = acc[p] * acc[p];
    __syncthreads();
    for (int s = 128; s > 0; s >>= 1) {
      if (t < s) { red1[t] += red1[t + s]; red2[t] += red2[t + s]; }
      __syncthreads();
    }
    float mu = red1[0] * (1.f / 256.f);
    float var = red2[0] * (1.f / 256.f) - mu * mu;
    float rstd = rsqrtf(var + 1e-5f);
    vals[p] = (acc[p] - mu) * rstd * g + be;
    __syncthreads();
  }
  #pragma unroll
  for (int p = 0; p < 9; ++p) s_ln[(size_t)img * 2304 + t * 9 + p] = vals[p];
  float mx = vals[0];
  #pragma unroll
  for (int p = 1; p < 9; ++p) mx = fmaxf(mx, vals[p]);
  int b = img / 3, e = img % 3;
  pooled[((size_t)b * 6 + e * 2 + (t >> 7)) * 128 + (t & 127)] = mx;
}

// fp16 MFMA implicit-GEMM conv3x3: 128x128 tile, round-8 staging (straight
// lane order — swizzle reverted: it broke request coalescing), double-buffered
// async global_load_lds, SPLIT-K=2: each half does 36 K-iters and atomicAdds
// its partial C into pre-zeroed offbuf/mskbuf (bias applied later in k_taps).
// Grid 72x2x12 = 1728 blocks (~6.75/CU) to fix the grid-limited occupancy.
__global__ void __launch_bounds__(256) k_conv3_mfma(
    const _Float16* __restrict__ qpad, const _Float16* __restrict__ Whf,
    float* __restrict__ offbuf, float* __restrict__ mskbuf) {
  int nb = blockIdx.x;
  int mb = blockIdx.y;
  int zz = blockIdx.z;         // 0..11 = half*6 + (d*2+b)
  int half = zz / 6;
  int z = zz - half * 6;
  int d = z >> 1, b = z & 1;
  int t = threadIdx.x;
  int lane = t & 63, wv = t >> 6;
  int wm = wv >> 1, wn = wv & 1;
  int quad = lane >> 4, l15 = lane & 15;

  __shared__ _Float16 __attribute__((aligned(16))) As[2 * 128 * 32];
  __shared__ _Float16 __attribute__((aligned(16))) Bs[2 * 128 * 32];

  // staging (per wave): lane i -> row wv*16 + (i>>2), chunk i&3
  int srow = wv * 16 + (lane >> 2);
  int qc = lane & 3;
  const _Float16* Wd = Whf + (size_t)d * 256 * 2304;
  const _Float16* aG1 = Wd + (size_t)(mb * 128 + srow) * 2304 + qc * 8;
  const _Float16* aG2 = aG1 + (size_t)64 * 2304;
  int px1 = nb * 128 + srow, px2 = px1 + 64;
  int h1 = px1 / 96, w1 = px1 - h1 * 96;
  int h2 = px2 / 96, w2 = px2 - h2 * 96;
  int ppx1 = (h1 + 4) * PCOL + w1 + 4;
  int ppx2 = (h2 + 4) * PCOL + w2 + 4;
  const _Float16* qb = qpad + (size_t)b * PPX * CC;
  const _Float16* bG1 = qb + (size_t)ppx1 * CC + qc * 8;
  const _Float16* bG2 = qb + (size_t)ppx2 * CC + qc * 8;

  char* AsB = (char*)As;
  char* BsB = (char*)Bs;
  int ldsOff1 = wv * 1024;
  int ldsOff2 = 4096 + wv * 1024;

  int aOff[4], bOff[4];
  #pragma unroll
  for (int i = 0; i < 4; ++i) {
    aOff[i] = (wm * 64 + i * 16 + l15) * 32 + quad * 8;
    bOff[i] = (wn * 64 + i * 16 + l15) * 32 + quad * 8;
  }

  f32x4 acc[16];
  #pragma unroll
  for (int i = 0; i < 16; ++i) acc[i] = (f32x4){0.f, 0.f, 0.f, 0.f};

  int g0 = half * 36;
  // prologue: global iter g0 into buffer 0
  {
    int ci0 = (g0 & 7) * 32;
    int jj = g0 >> 3;
    int offp = (jj / 3 - 1) * PCOL + (jj % 3 - 1);
    int kbase = g0 * 32;
    int boff = offp * CC + ci0;
    gload_lds16(aG1 + kbase, AsB + ldsOff1);
    gload_lds16(aG2 + kbase, AsB + ldsOff2);
    gload_lds16(bG1 + boff, BsB + ldsOff1);
    gload_lds16(bG2 + boff, BsB + ldsOff2);
  }
  __syncthreads();

  for (int iter = 0; iter < 36; ++iter) {
    int cur = iter & 1;
    if (iter < 35) {
      int g = g0 + iter + 1;
      int ci0 = (g & 7) * 32;
      int jj = g >> 3;
      int offp = (jj / 3 - 1) * PCOL + (jj % 3 - 1);   // dilation-1 taps for ALL d
      int kbase = g * 32;
      int boff = offp * CC + ci0;
      int nxb = (cur ^ 1) * 8192;
      gload_lds16(aG1 + kbase, AsB + nxb + ldsOff1);
      gload_lds16(aG2 + kbase, AsB + nxb + ldsOff2);
      gload_lds16(bG1 + boff, BsB + nxb + ldsOff1);
      gload_lds16(bG2 + boff, BsB + nxb + ldsOff2);
    }
    const _Float16* Ac = As + cur * 4096;
    const _Float16* Bc = Bs + cur * 4096;
    f16x8 af[4], bf[4];
    #pragma unroll
    for (int i = 0; i < 4; ++i) {
      af[i] = *(const f16x8*)(Ac + aOff[i]);
      bf[i] = *(const f16x8*)(Bc + bOff[i]);
    }
    #pragma unroll
    for (int mi = 0; mi < 4; ++mi)
      #pragma unroll
      for (int ni = 0; ni < 4; ++ni)
        acc[mi * 4 + ni] = __builtin_amdgcn_mfma_f32_16x16x32_f16(af[mi], bf[ni], acc[mi * 4 + ni], 0, 0, 0);
    __syncthreads();
  }

  // epilogue: atomic accumulate partial C (bias added in k_taps)
  #pragma unroll
  for (int mi = 0; mi < 4; ++mi) {
    int coB = mb * 128 + wm * 64 + mi * 16 + quad * 4;
    #pragma unroll
    for (int ni = 0; ni < 4; ++ni) {
      int px = nb * 128 + wn * 64 + ni * 16 + l15;
      f32x4 v = acc[mi * 4 + ni];
      #pragma unroll
      for (int r = 0; r < 4; ++r) {
        int c2 = coB + r;
        if (c2 < 216) {
          float* dst;
          if (c2 < 144) dst = &offbuf[((size_t)(d * BB + b) * 144 + c2) * HW + px];
          else          dst = &mskbuf[((size_t)(d * BB + b) * 72 + (c2 - 144)) * HW + px];
          atomicAdd(dst, v[r]);
        }
      }
    }
  }
}

// fused softmax + tap records, 8 threads per (z,px); adds conv biases here
// (conv3 halves wrote raw partial sums).
__global__ void k_taps(const float* __restrict__ offbuf, const float* __restrict__ mskbuf,
                       const float* __restrict__ Ball, unsigned int* __restrict__ taprec) {
  int t = threadIdx.x;
  int sub = t & 7, pxl = t >> 3;       // 32 px per block
  int bx = blockIdx.x;                 // 1728 blocks = 6 z * 288
  int z = bx / 288;
  int px = (bx - z * 288) * 32 + pxl;
  int d = z >> 1;
  const float* Bd = Ball + d * 256;
  const float* mp = mskbuf + (size_t)z * 72 * HW + px;
  float lg[9];
  float mx = -1e30f;
  #pragma unroll
  for (int j = 0; j < 9; ++j) {
    int tk = sub + 8 * j;
    lg[j] = mp[(size_t)tk * HW] + Bd[144 + tk];
    mx = fmaxf(mx, lg[j]);
  }
  mx = fmaxf(mx, __shfl_xor(mx, 1));
  mx = fmaxf(mx, __shfl_xor(mx, 2));
  mx = fmaxf(mx, __shfl_xor(mx, 4));
  float s = 0.f;
  #pragma unroll
  for (int j = 0; j < 9; ++j) s += __expf(lg[j] - mx);
  s += __shfl_xor(s, 1);
  s += __shfl_xor(s, 2);
  s += __shfl_xor(s, 4);
  float rinv = 1.f / s;
  int dil = 1 << (z >> 1);
  int h = px / WWID, w = px - h * WWID;
  const float* ob = offbuf + (size_t)z * 144 * HW + px;
  int k = sub;   // k = tk % 9, tk = sub + 8j  -> k advances by 8 mod 9
  #pragma unroll
  for (int j = 0; j < 9; ++j) {
    int tk = sub + 8 * j;
    float dy = ob[(size_t)(tk * 2 + 0) * HW] + Bd[tk * 2 + 0];
    float dx = ob[(size_t)(tk * 2 + 1) * HW] + Bd[tk * 2 + 1];
    float m = __expf(lg[j] - mx) * rinv;
    float py = (float)(h + (k / 3) * dil - dil) + dy;
    float pxx = (float)(w + (k % 3) * dil - dil) + dx;
    float y0f = floorf(py), x0f = floorf(pxx);
    int y0 = (int)y0f, x0 = (int)x0f;
    float wy = py - y0f, wx = pxx - x0f;
    bool vy0 = (unsigned)y0 < 96u, vy1 = (unsigned)(y0 + 1) < 96u;
    bool vx0 = (unsigned)x0 < 96u, vx1 = (unsigned)(x0 + 1) < 96u;
    float w00 = (vy0 && vx0) ? (1.f - wy) * (1.f - wx) * m : 0.f;
    float w01 = (vy0 && vx1) ? (1.f - wy) * wx * m : 0.f;
    float w10 = (vy1 && vx0) ? wy * (1.f - wx) * m : 0.f;
    float w11 = (vy1 && vx1) ? wy * wx * m : 0.f;
    int iy = min(max(y0 + 4, 0), 102);
    int ix = min(max(x0 + 4, 0), 126);
    unsigned int* r = taprec + (((size_t)(z * 72 + tk)) * HW + px) * 3;
    r[0] = pack2h(w00, w01);
    r[1] = pack2h(w10, w11);
    r[2] = (unsigned int)(iy * PCOL + ix);
    k += 8; if (k >= 9) k -= 9;
  }
}

// sim0 branch: grouped 1x1 with pooled weights. block = 8 px x 32 lanes.
__global__ void k_sim0(const float* __restrict__ qt, const float* __restrict__ pooled,
                       float* __restrict__ sim) {
  int b = blockIdx.z, h = blockIdx.y, seg = blockIdx.x;
  int t = threadIdx.x;
  int pxl = t >> 5, lane = t & 31;
  int wcol = seg * 8 + pxl;
  int hw = h * WWID + wcol;
  __shared__ float plds[768];
  for (int i = t; i < 768; i += 256) plds[i] = pooled[(size_t)b * 768 + i];
  __syncthreads();
  const float* qtb = qt + (size_t)b * HW * CC;
  float acc[6] = {0.f, 0.f, 0.f, 0.f, 0.f, 0.f};
  #pragma unroll
  for (int m = 0; m < 8; ++m) {
    int cfull = m * 32 + lane;
    float qv = qtb[(size_t)hw * CC + cfull];
    if (m < 4) {
      int cp = cfull;
      acc[0] += plds[0 * 128 + cp] * qv;
      acc[1] += plds[1 * 128 + cp] * qv;
      acc[2] += plds[2 * 128 + cp] * qv;
    } else {
      int cp = cfull - 128;
      acc[3] += plds[3 * 128 + cp] * qv;
      acc[4] += plds[4 * 128 + cp] * qv;
      acc[5] += plds[5 * 128 + cp] * qv;
    }
  }
  #pragma unroll
  for (int r = 0; r < 6; ++r) {
    float v = acc[r];
    #pragma unroll
    for (int off = 16; off; off >>= 1) v += __shfl_down(v, off, 32);
    if (lane == 0) sim[((size_t)b * 24 + r) * HW + hw] = v;
  }
}

// deformable conv v3: LDS-staged tap records + fp16 qpad gathers.
__global__ void __launch_bounds__(256) k_deform(
    const _Float16* __restrict__ qpad, const unsigned int* __restrict__ taprec,
    const float* __restrict__ s_ln, float* __restrict__ sim) {
  int z = blockIdx.z;
  int d_idx = z >> 1, b = z & 1;
  int seg = blockIdx.x;
  int t = threadIdx.x;
  int g = t >> 5, lane = t & 31;
  int half16 = lane >> 4, l16 = lane & 15;
  __shared__ float wlds[6912];
  __shared__ unsigned int tlds[6912];   // [72 tk][32 pxl][3]
  int px0 = seg * 32;
  for (int i = t; i < 6912; i += 256) wlds[i] = s_ln[(size_t)b * 6912 + i];
  {
    const unsigned int* tz = taprec + (size_t)z * 72 * HW * 3;
    for (int i = t; i < 6912; i += 256) {
      int tk = i / 96, rem = i - tk * 96;
      tlds[i] = tz[((size_t)tk * HW + px0) * 3 + rem];
    }
  }
  __syncthreads();
  int pg = g * 4;
  const _Float16* qb = qpad + (size_t)b * PPX * CC;

  float accA[4][3], accB[4][3];
  #pragma unroll
  for (int p = 0; p < 4; ++p)
    #pragma unroll
    for (int r = 0; r < 3; ++r) { accA[p][r] = 0.f; accB[p][r] = 0.f; }

  // og 0..3 -> rows 0..2 (s_ln bases 0/128/256)
  #pragma unroll 1
  for (int ogp = 0; ogp < 2; ++ogp) {
    int og = ogp * 2 + half16;
    int cp = og * 32 + l16 * 2;        // 0..126
    const _Float16* qc = qb + cp;
    #pragma unroll 1
    for (int k = 0; k < 9; ++k) {
      int tk = og * 9 + k;
      float w0a = wlds[(cp) * 9 + k],       w0b = wlds[(cp + 1) * 9 + k];
      float w1a = wlds[(128 + cp) * 9 + k], w1b = wlds[(129 + cp) * 9 + k];
      float w2a = wlds[(256 + cp) * 9 + k], w2b = wlds[(257 + cp) * 9 + k];
      const unsigned int* rp = &tlds[(tk * 32 + pg) * 3];
      #pragma unroll
      for (int p = 0; p < 4; ++p) {
        unsigned int u0 = rp[p * 3 + 0];
        unsigned int u1 = rp[p * 3 + 1];
        int idx = (int)rp[p * 3 + 2];
        const unsigned int* bp = (const unsigned int*)(qc + (size_t)idx * CC);
        unsigned int q00 = bp[0];
        unsigned int q01 = bp[CC / 2];
        unsigned int q10 = bp[128 * CC / 2];
        unsigned int q11 = bp[129 * CC / 2];
        float w00 = h_lo(u0), w01 = h_hi(u0), w10 = h_lo(u1), w11 = h_hi(u1);
        float sA = w00 * h_lo(q00) + w01 * h_lo(q01) + w10 * h_lo(q10) + w11 * h_lo(q11);
        float sB = w00 * h_hi(q00) + w01 * h_hi(q01) + w10 * h_hi(q10) + w11 * h_hi(q11);
        accA[p][0] += w0a * sA + w0b * sB;
        accA[p][1] += w1a * sA + w1b * sB;
        accA[p][2] += w2a * sA + w2b * sB;
      }
    }
  }

  // og 4..7 -> rows 3..5 (s_ln bases 384/512/640)
  #pragma unroll 1
  for (int ogp = 0; ogp < 2; ++ogp) {
    int og = 4 + ogp * 2 + half16;
    int c0 = og * 32 + l16 * 2;        // 128..254
    int cp = c0 - 128;
    const _Float16* qc = qb + c0;
    #pragma unroll 1
    for (int k = 0; k < 9; ++k) {
      int tk = og * 9 + k;
      float w0a = wlds[(384 + cp) * 9 + k], w0b = wlds[(385 + cp) * 9 + k];
      float w1a = wlds[(512 + cp) * 9 + k], w1b = wlds[(513 + cp) * 9 + k];
      float w2a = wlds[(640 + cp) * 9 + k], w2b = wlds[(641 + cp) * 9 + k];
      const unsigned int* rp = &tlds[(tk * 32 + pg) * 3];
      #pragma unroll
      for (int p = 0; p < 4; ++p) {
        unsigned int u0 = rp[p * 3 + 0];
        unsigned int u1 = rp[p * 3 + 1];
        int idx = (int)rp[p * 3 + 2];
        const unsigned int* bp = (const unsigned int*)(qc + (size_t)idx * CC);
        unsigned int q00 = bp[0];
        unsigned int q01 = bp[CC / 2];
        unsigned int q10 = bp[128 * CC / 2];
        unsigned int q11 = bp[129 * CC / 2];
        float w00 = h_lo(u0), w01 = h_hi(u0), w10 = h_lo(u1), w11 = h_hi(u1);
        float sA = w00 * h_lo(q00) + w01 * h_lo(q01) + w10 * h_lo(q10) + w11 * h_lo(q11);
        float sB = w00 * h_hi(q00) + w01 * h_hi(q01) + w10 * h_hi(q10) + w11 * h_hi(q11);
        accB[p][0] += w0a * sA + w0b * sB;
        accB[p][1] += w1a * sA + w1b * sB;
        accB[p][2] += w2a * sA + w2b * sB;
      }
    }
  }

  #pragma unroll
  for (int p = 0; p < 4; ++p) {
    #pragma unroll
    for (int r = 0; r < 3; ++r) {
      float v = accA[p][r];
      #pragma unroll
      for (int off = 16; off; off >>= 1) v += __shfl_down(v, off, 32);
      if (lane == 0) sim[((size_t)b * 24 + 6 + 6 * d_idx + r) * HW + px0 + pg + p] = v;
      float v2 = accB[p][r];
      #pragma unroll
      for (int off = 16; off; off >>= 1) v2 += __shfl_down(v2, off, 32);
      if (lane == 0) sim[((size_t)b * 24 + 6 + 6 * d_idx + 3 + r) * HW + px0 + pg + p] = v2;
    }
  }
}

// out 1x1 conv: sim [B][24][HW] x out_w [256][24] -> out [B][256][HW]
__global__ void k_outconv(const float* __restrict__ sim, const float* __restrict__ out_w,
                          const float* __restrict__ out_b, float* __restrict__ out) {
  int hw = blockIdx.x * 256 + threadIdx.x;
  int co = blockIdx.y, b = blockIdx.z;
  const float* simb = sim + (size_t)b * 24 * HW;
  float a = out_b[co];
  #pragma unroll
  for (int r = 0; r < 24; ++r) a += out_w[co * 24 + r] * simb[(size_t)r * HW + hw];
  out[((size_t)b * CC + co) * HW + hw] = a;
}

extern "C" void kernel_launch(void* const* d_in, const int* in_sizes, int n_in,
                              void* d_out, int out_size, void* d_ws, size_t ws_size,
                              hipStream_t stream) {
  const float* querys = (const float*)d_in[0];
  const float* sup    = (const float*)d_in[1];
  const float* in_w   = (const float*)d_in[2];
  const float* in_b   = (const float*)d_in[3];
  const float* ln_g   = (const float*)d_in[4];
  const float* ln_b   = (const float*)d_in[5];
  const float* out_w  = (const float*)d_in[6];
  const float* out_b  = (const float*)d_in[7];
  const float* ow1 = (const float*)d_in[8];
  const float* ob1 = (const float*)d_in[9];
  const float* mw1 = (const float*)d_in[10];
  const float* mb1 = (const float*)d_in[11];
  const float* ow2 = (const float*)d_in[12];
  const float* ob2 = (const float*)d_in[13];
  const float* mw2 = (const float*)d_in[14];
  const float* mb2 = (const float*)d_in[15];
  const float* ow4 = (const float*)d_in[16];
  const float* ob4 = (const float*)d_in[17];
  const float* mw4 = (const float*)d_in[18];
  const float* mb4 = (const float*)d_in[19];
  float* out = (float*)d_out;

  float* ws_f   = (float*)d_ws;
  float* wT     = ws_f;                              // 65536 floats
  _Float16* Whf = (_Float16*)(wT + 65536);           // 884736 float slots
  float* Ball   = (float*)(Whf + 3 * 256 * 2304);    // 768 (pad 1024)
  float* q_hwc  = Ball + 1024;                       // 4718592
  _Float16* qpad = (_Float16*)(q_hwc + (size_t)BB * HW * CC);  // 3407872 float slots
  float* s_ln   = (float*)(qpad + (size_t)BB * PPX * CC);  // 13824
  float* pooled = s_ln + 13824;                      // 1536
  float* offbuf = pooled + 1536;                     // 7962624
  float* mskbuf = offbuf + (size_t)3 * BB * 144 * HW;  // 3981312 (contiguous after offbuf)
  float* sim    = mskbuf + (size_t)3 * BB * 72 * HW;   // 442368
  unsigned int* taprec = (unsigned int*)(sim + (size_t)BB * 24 * HW);  // 11943936 dwords

  hipMemsetAsync(qpad, 0, (size_t)BB * PPX * CC * sizeof(_Float16), stream);
  hipMemsetAsync(offbuf, 0, (size_t)(7962624 + 3981312) * sizeof(float), stream);
  k_transpose_w<<<dim3(256), dim3(256), 0, stream>>>(in_w, wT);
  k_packw<<<dim3((3 * 256 * 2304 + 255) / 256), dim3(256), 0, stream>>>(
      ow1, ob1, mw1, mb1, ow2, ob2, mw2, mb2, ow4, ob4, mw4, mb4, Whf, Ball);
  k_conv1_ln_q<<<dim3(576), dim3(256), 0, stream>>>(querys, wT, in_b, ln_g, ln_b, q_hwc, qpad);
  k_conv1_ln_s<<<dim3(6), dim3(256), 0, stream>>>(sup, wT, in_b, ln_g, ln_b, s_ln, pooled);
  k_conv3_mfma<<<dim3(72, 2, 12), dim3(256), 0, stream>>>(qpad, Whf, offbuf, mskbuf);
  k_taps<<<dim3(1728), dim3(256), 0, stream>>>(offbuf, mskbuf, Ball, taprec);
  k_sim0<<<dim3(12, 96, BB), dim3(256), 0, stream>>>(q_hwc, pooled, sim);
  k_deform<<<dim3(288, 1, 6), dim3(256), 0, stream>>>(qpad, taprec, s_ln, sim);
  k_outconv<<<dim3(36, 256, BB), dim3(256), 0, stream>>>(sim, out_w, out_b, out);
}

// Round 12
// 439.002 us; speedup vs baseline: 1.1233x; 1.1233x over previous
//
#include <hip/hip_runtime.h>
#include <hip/hip_bf16.h>
#include <math.h>

#define HH 96
#define WWID 96
#define HW 9216
#define CC 256
#define BB 2
#define PROW 104
#define PCOL 128
#define PPX (PROW * PCOL)   // 13312

typedef float f32x4 __attribute__((ext_vector_type(4)));
typedef _Float16 f16x8 __attribute__((ext_vector_type(8)));

__device__ inline unsigned int pack2h(float a, float b) {
  unsigned short ua = __builtin_bit_cast(unsigned short, (_Float16)a);
  unsigned short ub = __builtin_bit_cast(unsigned short, (_Float16)b);
  return (unsigned int)ua | ((unsigned int)ub << 16);
}
__device__ inline float h_lo(unsigned int u) {
  return (float)__builtin_bit_cast(_Float16, (unsigned short)(u & 0xffffu));
}
__device__ inline float h_hi(unsigned int u) {
  return (float)__builtin_bit_cast(_Float16, (unsigned short)(u >> 16));
}

// async 16B global->LDS: lds dest = wave-uniform base + lane*16
__device__ inline void gload_lds16(const void* g, void* l) {
  __builtin_amdgcn_global_load_lds(
      (const __attribute__((address_space(1))) void*)g,
      (__attribute__((address_space(3))) void*)l, 16, 0, 0);
}

// in_w [C][C] -> wT [k][c]
__global__ void k_transpose_w(const float* __restrict__ in_w, float* __restrict__ wT) {
  int k = blockIdx.x, c = threadIdx.x;
  wT[k * CC + c] = in_w[c * CC + k];
}

// pack conv3x3 weights -> Whf [3 d][256 co][2304 k], k = j*256+ci, fp16; bias Ball[3*256]
__global__ void k_packw(const float* __restrict__ ow1, const float* __restrict__ ob1,
                        const float* __restrict__ mw1, const float* __restrict__ mb1,
                        const float* __restrict__ ow2, const float* __restrict__ ob2,
                        const float* __restrict__ mw2, const float* __restrict__ mb2,
                        const float* __restrict__ ow4, const float* __restrict__ ob4,
                        const float* __restrict__ mw4, const float* __restrict__ mb4,
                        _Float16* __restrict__ Whf, float* __restrict__ Ball) {
  int idx = blockIdx.x * 256 + threadIdx.x;
  if (idx >= 3 * 256 * 2304) return;
  int d = idx / (256 * 2304);
  int rem = idx - d * 256 * 2304;
  int co = rem / 2304;
  int k = rem - co * 2304;
  int j = k >> 8, ci = k & 255;
  const float* ow = d == 0 ? ow1 : (d == 1 ? ow2 : ow4);
  const float* mw = d == 0 ? mw1 : (d == 1 ? mw2 : mw4);
  float v = 0.f;
  if (co < 144) v = ow[co * 2304 + ci * 9 + j];
  else if (co < 216) v = mw[(co - 144) * 2304 + ci * 9 + j];
  Whf[idx] = (_Float16)v;
  if (idx < 768) {
    int dd = idx >> 8, cc = idx & 255;
    const float* obv = dd == 0 ? ob1 : (dd == 1 ? ob2 : ob4);
    const float* mbv = dd == 0 ? mb1 : (dd == 1 ? mb2 : mb4);
    float bv = 0.f;
    if (cc < 144) bv = obv[cc];
    else if (cc < 216) bv = mbv[cc - 144];
    Ball[idx] = bv;
  }
}

// conv1x1 + LayerNorm for the query. Writes fp32 NHWC q_hwc AND fp16 qpad
// (zero-padded grid; border pre-zeroed by hipMemsetAsync). float4 LDS reads.
__global__ void k_conv1_ln_q(const float* __restrict__ qin, const float* __restrict__ wT,
                             const float* __restrict__ in_b, const float* __restrict__ ln_g,
                             const float* __restrict__ ln_b, float* __restrict__ q_hwc,
                             _Float16* __restrict__ qpad) {
  int bx = blockIdx.x;
  int b = bx / 288;
  int hw0 = (bx % 288) * 32;
  int t = threadIdx.x;
  int lane = t & 63;
  int wv_id = t >> 6;
  __shared__ float xs[32 * 260];
  const float* qb = qin + (size_t)b * CC * HW;
  #pragma unroll
  for (int i = 0; i < 32; ++i) {
    int idx = t + i * 256;
    int p = idx & 31;
    int k = idx >> 5;
    xs[p * 260 + k] = qb[k * HW + hw0 + p];
  }
  __syncthreads();
  float acc[8][4];
  #pragma unroll
  for (int p = 0; p < 8; ++p) { acc[p][0]=0.f; acc[p][1]=0.f; acc[p][2]=0.f; acc[p][3]=0.f; }
  const float4* wT4 = (const float4*)wT;
  int p0 = wv_id * 8;
  for (int k = 0; k < 256; k += 4) {
    float4 w0 = wT4[(k + 0) * 64 + lane];
    float4 w1 = wT4[(k + 1) * 64 + lane];
    float4 w2 = wT4[(k + 2) * 64 + lane];
    float4 w3 = wT4[(k + 3) * 64 + lane];
    #pragma unroll
    for (int p = 0; p < 8; ++p) {
      float4 xv = *(const float4*)&xs[(p0 + p) * 260 + k];
      acc[p][0] += w0.x * xv.x + w1.x * xv.y + w2.x * xv.z + w3.x * xv.w;
      acc[p][1] += w0.y * xv.x + w1.y * xv.y + w2.y * xv.z + w3.y * xv.w;
      acc[p][2] += w0.z * xv.x + w1.z * xv.y + w2.z * xv.z + w3.z * xv.w;
      acc[p][3] += w0.w * xv.x + w1.w * xv.y + w2.w * xv.z + w3.w * xv.w;
    }
  }
  float4 bb = ((const float4*)in_b)[lane];
  float4 g4 = ((const float4*)ln_g)[lane];
  float4 b4 = ((const float4*)ln_b)[lane];
  #pragma unroll
  for (int p = 0; p < 8; ++p) {
    float y0 = acc[p][0] + bb.x, y1 = acc[p][1] + bb.y;
    float y2 = acc[p][2] + bb.z, y3 = acc[p][3] + bb.w;
    float s1 = y0 + y1 + y2 + y3;
    float s2 = y0*y0 + y1*y1 + y2*y2 + y3*y3;
    #pragma unroll
    for (int off = 32; off; off >>= 1) { s1 += __shfl_xor(s1, off); s2 += __shfl_xor(s2, off); }
    float mu = s1 * (1.f / 256.f);
    float rstd = rsqrtf(s2 * (1.f / 256.f) - mu * mu + 1e-5f);
    float4 o;
    o.x = (y0 - mu) * rstd * g4.x + b4.x;
    o.y = (y1 - mu) * rstd * g4.y + b4.y;
    o.z = (y2 - mu) * rstd * g4.z + b4.z;
    o.w = (y3 - mu) * rstd * g4.w + b4.w;
    int hw = hw0 + p0 + p;
    ((float4*)q_hwc)[((size_t)b * HW + hw) * 64 + lane] = o;
    int hh = hw / 96, ww = hw - hh * 96;
    int ppx = (hh + 4) * PCOL + ww + 4;
    struct alignas(8) h4 { _Float16 h[4]; };
    h4 oh;
    oh.h[0] = (_Float16)o.x; oh.h[1] = (_Float16)o.y;
    oh.h[2] = (_Float16)o.z; oh.h[3] = (_Float16)o.w;
    *(h4*)(qpad + ((size_t)b * PPX + ppx) * CC + lane * 4) = oh;
  }
}

// supports: conv1x1 + LN per (b,e) image of 9 positions; also pooled max.
__global__ void k_conv1_ln_s(const float* __restrict__ sup, const float* __restrict__ wT,
                             const float* __restrict__ in_b, const float* __restrict__ ln_g,
                             const float* __restrict__ ln_b, float* __restrict__ s_ln,
                             float* __restrict__ pooled) {
  int img = blockIdx.x;  // b*3+e
  int t = threadIdx.x;
  __shared__ float xs[2304];
  __shared__ float red1[256], red2[256];
  #pragma unroll
  for (int p = 0; p < 9; ++p) xs[t * 9 + p] = sup[(size_t)img * 2304 + t * 9 + p];
  __syncthreads();
  float acc[9];
  #pragma unroll
  for (int p = 0; p < 9; ++p) acc[p] = 0.f;
  for (int k = 0; k < 256; ++k) {
    float wv = wT[k * CC + t];
    #pragma unroll
    for (int p = 0; p < 9; ++p) acc[p] += wv * xs[k * 9 + p];
  }
  float bias = in_b[t];
  #pragma unroll
  for (int p = 0; p < 9; ++p) acc[p] += bias;
  float g = ln_g[t], be = ln_b[t];
  float vals[9];
  #pragma unroll
  for (int p = 0; p < 9; ++p) {
    red1[t] = acc[p]; red2[t] = acc[p] * acc[p];
    __syncthreads();
    for (int s = 128; s > 0; s >>= 1) {
      if (t < s) { red1[t] += red1[t + s]; red2[t] += red2[t + s]; }
      __syncthreads();
    }
    float mu = red1[0] * (1.f / 256.f);
    float var = red2[0] * (1.f / 256.f) - mu * mu;
    float rstd = rsqrtf(var + 1e-5f);
    vals[p] = (acc[p] - mu) * rstd * g + be;
    __syncthreads();
  }
  #pragma unroll
  for (int p = 0; p < 9; ++p) s_ln[(size_t)img * 2304 + t * 9 + p] = vals[p];
  float mx = vals[0];
  #pragma unroll
  for (int p = 1; p < 9; ++p) mx = fmaxf(mx, vals[p]);
  int b = img / 3, e = img % 3;
  pooled[((size_t)b * 6 + e * 2 + (t >> 7)) * 128 + (t & 127)] = mx;
}

// fp16 MFMA implicit-GEMM conv3x3: 128x128 tile, double-buffered async
// global_load_lds (round-8 config — best measured of 6 structural variants;
// split-K/atomics and LDS swizzle both regressed). Direct stores, no bias
// (bias added in k_taps).
__global__ void __launch_bounds__(256) k_conv3_mfma(
    const _Float16* __restrict__ qpad, const _Float16* __restrict__ Whf,
    float* __restrict__ offbuf, float* __restrict__ mskbuf) {
  int nb = blockIdx.x;
  int mb = blockIdx.y;
  int z = blockIdx.z;
  int d = z >> 1, b = z & 1;
  int t = threadIdx.x;
  int lane = t & 63, wv = t >> 6;
  int wm = wv >> 1, wn = wv & 1;
  int quad = lane >> 4, l15 = lane & 15;

  __shared__ _Float16 __attribute__((aligned(16))) As[2 * 128 * 32];
  __shared__ _Float16 __attribute__((aligned(16))) Bs[2 * 128 * 32];

  int srow = wv * 16 + (lane >> 2);
  int qc = lane & 3;
  const _Float16* Wd = Whf + (size_t)d * 256 * 2304;
  const _Float16* aG1 = Wd + (size_t)(mb * 128 + srow) * 2304 + qc * 8;
  const _Float16* aG2 = aG1 + (size_t)64 * 2304;
  int px1 = nb * 128 + srow, px2 = px1 + 64;
  int h1 = px1 / 96, w1 = px1 - h1 * 96;
  int h2 = px2 / 96, w2 = px2 - h2 * 96;
  int ppx1 = (h1 + 4) * PCOL + w1 + 4;
  int ppx2 = (h2 + 4) * PCOL + w2 + 4;
  const _Float16* qb = qpad + (size_t)b * PPX * CC;
  const _Float16* bG1 = qb + (size_t)ppx1 * CC + qc * 8;
  const _Float16* bG2 = qb + (size_t)ppx2 * CC + qc * 8;

  char* AsB = (char*)As;
  char* BsB = (char*)Bs;
  int ldsOff1 = wv * 1024;
  int ldsOff2 = 4096 + wv * 1024;

  int aOff[4], bOff[4];
  #pragma unroll
  for (int i = 0; i < 4; ++i) {
    aOff[i] = (wm * 64 + i * 16 + l15) * 32 + quad * 8;
    bOff[i] = (wn * 64 + i * 16 + l15) * 32 + quad * 8;
  }

  f32x4 acc[16];
  #pragma unroll
  for (int i = 0; i < 16; ++i) acc[i] = (f32x4){0.f, 0.f, 0.f, 0.f};

  {
    int boff0 = (-PCOL - 1) * CC;
    gload_lds16(aG1, AsB + ldsOff1);
    gload_lds16(aG2, AsB + ldsOff2);
    gload_lds16(bG1 + boff0, BsB + ldsOff1);
    gload_lds16(bG2 + boff0, BsB + ldsOff2);
  }
  __syncthreads();

  for (int iter = 0; iter < 72; ++iter) {
    int cur = iter & 1;
    if (iter < 71) {
      int it = iter + 1;
      int ci0 = (it & 7) * 32;
      int jj = it >> 3;
      int offp = (jj / 3 - 1) * PCOL + (jj % 3 - 1);   // dilation-1 taps for ALL d
      int kbase = it * 32;
      int boff = offp * CC + ci0;
      int nxb = (cur ^ 1) * 8192;
      gload_lds16(aG1 + kbase, AsB + nxb + ldsOff1);
      gload_lds16(aG2 + kbase, AsB + nxb + ldsOff2);
      gload_lds16(bG1 + boff, BsB + nxb + ldsOff1);
      gload_lds16(bG2 + boff, BsB + nxb + ldsOff2);
    }
    const _Float16* Ac = As + cur * 4096;
    const _Float16* Bc = Bs + cur * 4096;
    f16x8 af[4], bf[4];
    #pragma unroll
    for (int i = 0; i < 4; ++i) {
      af[i] = *(const f16x8*)(Ac + aOff[i]);
      bf[i] = *(const f16x8*)(Bc + bOff[i]);
    }
    #pragma unroll
    for (int mi = 0; mi < 4; ++mi)
      #pragma unroll
      for (int ni = 0; ni < 4; ++ni)
        acc[mi * 4 + ni] = __builtin_amdgcn_mfma_f32_16x16x32_f16(af[mi], bf[ni], acc[mi * 4 + ni], 0, 0, 0);
    __syncthreads();
  }

  #pragma unroll
  for (int mi = 0; mi < 4; ++mi) {
    int coB = mb * 128 + wm * 64 + mi * 16 + quad * 4;
    #pragma unroll
    for (int ni = 0; ni < 4; ++ni) {
      int px = nb * 128 + wn * 64 + ni * 16 + l15;
      f32x4 v = acc[mi * 4 + ni];
      #pragma unroll
      for (int r = 0; r < 4; ++r) {
        int c2 = coB + r;
        if (c2 < 216) {
          if (c2 < 144) offbuf[((size_t)(d * BB + b) * 144 + c2) * HW + px] = v[r];
          else mskbuf[((size_t)(d * BB + b) * 72 + (c2 - 144)) * HW + px] = v[r];
        }
      }
    }
  }
}

// fused softmax + tap records, 8 threads per (z,px); adds conv biases here
// (conv3 writes raw GEMM output).
__global__ void k_taps(const float* __restrict__ offbuf, const float* __restrict__ mskbuf,
                       const float* __restrict__ Ball, unsigned int* __restrict__ taprec) {
  int t = threadIdx.x;
  int sub = t & 7, pxl = t >> 3;       // 32 px per block
  int bx = blockIdx.x;                 // 1728 blocks = 6 z * 288
  int z = bx / 288;
  int px = (bx - z * 288) * 32 + pxl;
  int d = z >> 1;
  const float* Bd = Ball + d * 256;
  const float* mp = mskbuf + (size_t)z * 72 * HW + px;
  float lg[9];
  float mx = -1e30f;
  #pragma unroll
  for (int j = 0; j < 9; ++j) {
    int tk = sub + 8 * j;
    lg[j] = mp[(size_t)tk * HW] + Bd[144 + tk];
    mx = fmaxf(mx, lg[j]);
  }
  mx = fmaxf(mx, __shfl_xor(mx, 1));
  mx = fmaxf(mx, __shfl_xor(mx, 2));
  mx = fmaxf(mx, __shfl_xor(mx, 4));
  float s = 0.f;
  #pragma unroll
  for (int j = 0; j < 9; ++j) s += __expf(lg[j] - mx);
  s += __shfl_xor(s, 1);
  s += __shfl_xor(s, 2);
  s += __shfl_xor(s, 4);
  float rinv = 1.f / s;
  int dil = 1 << (z >> 1);
  int h = px / WWID, w = px - h * WWID;
  const float* ob = offbuf + (size_t)z * 144 * HW + px;
  int k = sub;   // k = tk % 9, tk = sub + 8j  -> k advances by 8 mod 9
  #pragma unroll
  for (int j = 0; j < 9; ++j) {
    int tk = sub + 8 * j;
    float dy = ob[(size_t)(tk * 2 + 0) * HW] + Bd[tk * 2 + 0];
    float dx = ob[(size_t)(tk * 2 + 1) * HW] + Bd[tk * 2 + 1];
    float m = __expf(lg[j] - mx) * rinv;
    float py = (float)(h + (k / 3) * dil - dil) + dy;
    float pxx = (float)(w + (k % 3) * dil - dil) + dx;
    float y0f = floorf(py), x0f = floorf(pxx);
    int y0 = (int)y0f, x0 = (int)x0f;
    float wy = py - y0f, wx = pxx - x0f;
    bool vy0 = (unsigned)y0 < 96u, vy1 = (unsigned)(y0 + 1) < 96u;
    bool vx0 = (unsigned)x0 < 96u, vx1 = (unsigned)(x0 + 1) < 96u;
    float w00 = (vy0 && vx0) ? (1.f - wy) * (1.f - wx) * m : 0.f;
    float w01 = (vy0 && vx1) ? (1.f - wy) * wx * m : 0.f;
    float w10 = (vy1 && vx0) ? wy * (1.f - wx) * m : 0.f;
    float w11 = (vy1 && vx1) ? wy * wx * m : 0.f;
    int iy = min(max(y0 + 4, 0), 102);
    int ix = min(max(x0 + 4, 0), 126);
    unsigned int* r = taprec + (((size_t)(z * 72 + tk)) * HW + px) * 3;
    r[0] = pack2h(w00, w01);
    r[1] = pack2h(w10, w11);
    r[2] = (unsigned int)(iy * PCOL + ix);
    k += 8; if (k >= 9) k -= 9;
  }
}

// sim0 branch: grouped 1x1 with pooled weights. block = 8 px x 32 lanes.
__global__ void k_sim0(const float* __restrict__ qt, const float* __restrict__ pooled,
                       float* __restrict__ sim) {
  int b = blockIdx.z, h = blockIdx.y, seg = blockIdx.x;
  int t = threadIdx.x;
  int pxl = t >> 5, lane = t & 31;
  int wcol = seg * 8 + pxl;
  int hw = h * WWID + wcol;
  __shared__ float plds[768];
  for (int i = t; i < 768; i += 256) plds[i] = pooled[(size_t)b * 768 + i];
  __syncthreads();
  const float* qtb = qt + (size_t)b * HW * CC;
  float acc[6] = {0.f, 0.f, 0.f, 0.f, 0.f, 0.f};
  #pragma unroll
  for (int m = 0; m < 8; ++m) {
    int cfull = m * 32 + lane;
    float qv = qtb[(size_t)hw * CC + cfull];
    if (m < 4) {
      int cp = cfull;
      acc[0] += plds[0 * 128 + cp] * qv;
      acc[1] += plds[1 * 128 + cp] * qv;
      acc[2] += plds[2 * 128 + cp] * qv;
    } else {
      int cp = cfull - 128;
      acc[3] += plds[3 * 128 + cp] * qv;
      acc[4] += plds[4 * 128 + cp] * qv;
      acc[5] += plds[5 * 128 + cp] * qv;
    }
  }
  #pragma unroll
  for (int r = 0; r < 6; ++r) {
    float v = acc[r];
    #pragma unroll
    for (int off = 16; off; off >>= 1) v += __shfl_down(v, off, 32);
    if (lane == 0) sim[((size_t)b * 24 + r) * HW + hw] = v;
  }
}

// deformable conv v4: fp16 weights in LDS ([k][ch] pair-packed, 13.8 KB) and
// tap records read DIRECT from global (uniform per 16-lane half -> L1-hit
// broadcast; block record set 27.6 KB fits L1). LDS 55->13.8 KB lifts
// occupancy 2 -> ~8 blocks/CU for gather-latency hiding.
__global__ void __launch_bounds__(256) k_deform(
    const _Float16* __restrict__ qpad, const unsigned int* __restrict__ taprec,
    const float* __restrict__ s_ln, float* __restrict__ sim) {
  int z = blockIdx.z;
  int d_idx = z >> 1, b = z & 1;
  int seg = blockIdx.x;
  int t = threadIdx.x;
  int g = t >> 5, lane = t & 31;
  int half16 = lane >> 4, l16 = lane & 15;
  __shared__ _Float16 wh[6912];          // [9 k][768 ch], pair-readable as dwords
  int px0 = seg * 32;
  for (int i = t; i < 6912; i += 256) {
    int c = i / 9, k = i % 9;
    wh[k * 768 + c] = (_Float16)s_ln[(size_t)b * 6912 + i];
  }
  __syncthreads();
  int pg = g * 4;
  const unsigned int* whd = (const unsigned int*)wh;   // dword idx = (k*768+c)>>1
  const unsigned int* tz = taprec + (size_t)z * 72 * HW * 3;
  const _Float16* qb = qpad + (size_t)b * PPX * CC;

  float accA[4][3], accB[4][3];
  #pragma unroll
  for (int p = 0; p < 4; ++p)
    #pragma unroll
    for (int r = 0; r < 3; ++r) { accA[p][r] = 0.f; accB[p][r] = 0.f; }

  // og 0..3 -> rows 0..2 (ch bases 0/128/256)
  #pragma unroll 1
  for (int ogp = 0; ogp < 2; ++ogp) {
    int og = ogp * 2 + half16;
    int cp = og * 32 + l16 * 2;        // 0..126, even
    const _Float16* qc = qb + cp;
    #pragma unroll 1
    for (int k = 0; k < 9; ++k) {
      int tk = og * 9 + k;
      unsigned int wp0 = whd[(k * 768 + cp) >> 1];
      unsigned int wp1 = whd[(k * 768 + 128 + cp) >> 1];
      unsigned int wp2 = whd[(k * 768 + 256 + cp) >> 1];
      float w0a = h_lo(wp0), w0b = h_hi(wp0);
      float w1a = h_lo(wp1), w1b = h_hi(wp1);
      float w2a = h_lo(wp2), w2b = h_hi(wp2);
      const unsigned int* rp = tz + ((size_t)tk * HW + px0 + pg) * 3;
      #pragma unroll
      for (int p = 0; p < 4; ++p) {
        unsigned int u0 = rp[p * 3 + 0];
        unsigned int u1 = rp[p * 3 + 1];
        int idx = (int)rp[p * 3 + 2];
        const unsigned int* bp = (const unsigned int*)(qc + (size_t)idx * CC);
        unsigned int q00 = bp[0];
        unsigned int q01 = bp[CC / 2];
        unsigned int q10 = bp[128 * CC / 2];
        unsigned int q11 = bp[129 * CC / 2];
        float w00 = h_lo(u0), w01 = h_hi(u0), w10 = h_lo(u1), w11 = h_hi(u1);
        float sA = w00 * h_lo(q00) + w01 * h_lo(q01) + w10 * h_lo(q10) + w11 * h_lo(q11);
        float sB = w00 * h_hi(q00) + w01 * h_hi(q01) + w10 * h_hi(q10) + w11 * h_hi(q11);
        accA[p][0] += w0a * sA + w0b * sB;
        accA[p][1] += w1a * sA + w1b * sB;
        accA[p][2] += w2a * sA + w2b * sB;
      }
    }
  }

  // og 4..7 -> rows 3..5 (ch bases 384/512/640)
  #pragma unroll 1
  for (int ogp = 0; ogp < 2; ++ogp) {
    int og = 4 + ogp * 2 + half16;
    int c0 = og * 32 + l16 * 2;        // 128..254
    int cp = c0 - 128;                 // 0..126, even
    const _Float16* qc = qb + c0;
    #pragma unroll 1
    for (int k = 0; k < 9; ++k) {
      int tk = og * 9 + k;
      unsigned int wp0 = whd[(k * 768 + 384 + cp) >> 1];
      unsigned int wp1 = whd[(k * 768 + 512 + cp) >> 1];
      unsigned int wp2 = whd[(k * 768 + 640 + cp) >> 1];
      float w0a = h_lo(wp0), w0b = h_hi(wp0);
      float w1a = h_lo(wp1), w1b = h_hi(wp1);
      float w2a = h_lo(wp2), w2b = h_hi(wp2);
      const unsigned int* rp = tz + ((size_t)tk * HW + px0 + pg) * 3;
      #pragma unroll
      for (int p = 0; p < 4; ++p) {
        unsigned int u0 = rp[p * 3 + 0];
        unsigned int u1 = rp[p * 3 + 1];
        int idx = (int)rp[p * 3 + 2];
        const unsigned int* bp = (const unsigned int*)(qc + (size_t)idx * CC);
        unsigned int q00 = bp[0];
        unsigned int q01 = bp[CC / 2];
        unsigned int q10 = bp[128 * CC / 2];
        unsigned int q11 = bp[129 * CC / 2];
        float w00 = h_lo(u0), w01 = h_hi(u0), w10 = h_lo(u1), w11 = h_hi(u1);
        float sA = w00 * h_lo(q00) + w01 * h_lo(q01) + w10 * h_lo(q10) + w11 * h_lo(q11);
        float sB = w00 * h_hi(q00) + w01 * h_hi(q01) + w10 * h_hi(q10) + w11 * h_hi(q11);
        accB[p][0] += w0a * sA + w0b * sB;
        accB[p][1] += w1a * sA + w1b * sB;
        accB[p][2] += w2a * sA + w2b * sB;
      }
    }
  }

  #pragma unroll
  for (int p = 0; p < 4; ++p) {
    #pragma unroll
    for (int r = 0; r < 3; ++r) {
      float v = accA[p][r];
      #pragma unroll
      for (int off = 16; off; off >>= 1) v += __shfl_down(v, off, 32);
      if (lane == 0) sim[((size_t)b * 24 + 6 + 6 * d_idx + r) * HW + px0 + pg + p] = v;
      float v2 = accB[p][r];
      #pragma unroll
      for (int off = 16; off; off >>= 1) v2 += __shfl_down(v2, off, 32);
      if (lane == 0) sim[((size_t)b * 24 + 6 + 6 * d_idx + 3 + r) * HW + px0 + pg + p] = v2;
    }
  }
}

// out 1x1 conv: sim [B][24][HW] x out_w [256][24] -> out [B][256][HW]
__global__ void k_outconv(const float* __restrict__ sim, const float* __restrict__ out_w,
                          const float* __restrict__ out_b, float* __restrict__ out) {
  int hw = blockIdx.x * 256 + threadIdx.x;
  int co = blockIdx.y, b = blockIdx.z;
  const float* simb = sim + (size_t)b * 24 * HW;
  float a = out_b[co];
  #pragma unroll
  for (int r = 0; r < 24; ++r) a += out_w[co * 24 + r] * simb[(size_t)r * HW + hw];
  out[((size_t)b * CC + co) * HW + hw] = a;
}

extern "C" void kernel_launch(void* const* d_in, const int* in_sizes, int n_in,
                              void* d_out, int out_size, void* d_ws, size_t ws_size,
                              hipStream_t stream) {
  const float* querys = (const float*)d_in[0];
  const float* sup    = (const float*)d_in[1];
  const float* in_w   = (const float*)d_in[2];
  const float* in_b   = (const float*)d_in[3];
  const float* ln_g   = (const float*)d_in[4];
  const float* ln_b   = (const float*)d_in[5];
  const float* out_w  = (const float*)d_in[6];
  const float* out_b  = (const float*)d_in[7];
  const float* ow1 = (const float*)d_in[8];
  const float* ob1 = (const float*)d_in[9];
  const float* mw1 = (const float*)d_in[10];
  const float* mb1 = (const float*)d_in[11];
  const float* ow2 = (const float*)d_in[12];
  const float* ob2 = (const float*)d_in[13];
  const float* mw2 = (const float*)d_in[14];
  const float* mb2 = (const float*)d_in[15];
  const float* ow4 = (const float*)d_in[16];
  const float* ob4 = (const float*)d_in[17];
  const float* mw4 = (const float*)d_in[18];
  const float* mb4 = (const float*)d_in[19];
  float* out = (float*)d_out;

  float* ws_f   = (float*)d_ws;
  float* wT     = ws_f;                              // 65536 floats
  _Float16* Whf = (_Float16*)(wT + 65536);           // 884736 float slots
  float* Ball   = (float*)(Whf + 3 * 256 * 2304);    // 768 (pad 1024)
  float* q_hwc  = Ball + 1024;                       // 4718592
  _Float16* qpad = (_Float16*)(q_hwc + (size_t)BB * HW * CC);  // 3407872 float slots
  float* s_ln   = (float*)(qpad + (size_t)BB * PPX * CC);  // 13824
  float* pooled = s_ln + 13824;                      // 1536
  float* offbuf = pooled + 1536;                     // 7962624
  float* mskbuf = offbuf + (size_t)3 * BB * 144 * HW;  // 3981312
  float* sim    = mskbuf + (size_t)3 * BB * 72 * HW;   // 442368
  unsigned int* taprec = (unsigned int*)(sim + (size_t)BB * 24 * HW);  // 11943936 dwords

  hipMemsetAsync(qpad, 0, (size_t)BB * PPX * CC * sizeof(_Float16), stream);
  k_transpose_w<<<dim3(256), dim3(256), 0, stream>>>(in_w, wT);
  k_packw<<<dim3((3 * 256 * 2304 + 255) / 256), dim3(256), 0, stream>>>(
      ow1, ob1, mw1, mb1, ow2, ob2, mw2, mb2, ow4, ob4, mw4, mb4, Whf, Ball);
  k_conv1_ln_q<<<dim3(576), dim3(256), 0, stream>>>(querys, wT, in_b, ln_g, ln_b, q_hwc, qpad);
  k_conv1_ln_s<<<dim3(6), dim3(256), 0, stream>>>(sup, wT, in_b, ln_g, ln_b, s_ln, pooled);
  k_conv3_mfma<<<dim3(72, 2, 6), dim3(256), 0, stream>>>(qpad, Whf, offbuf, mskbuf);
  k_taps<<<dim3(1728), dim3(256), 0, stream>>>(offbuf, mskbuf, Ball, taprec);
  k_sim0<<<dim3(12, 96, BB), dim3(256), 0, stream>>>(q_hwc, pooled, sim);
  k_deform<<<dim3(288, 1, 6), dim3(256), 0, stream>>>(qpad, taprec, s_ln, sim);
  k_outconv<<<dim3(36, 256, BB), dim3(256), 0, stream>>>(sim, out_w, out_b, out);
}